// Round 7
// baseline (91.342 us; speedup 1.0000x reference)
//
#include <hip/hip_runtime.h>
#include <hip/hip_bf16.h>

#define B_ 2
#define S_ 1024
#define E_ 128
#define H_ 4
#define D_ 32
#define BHSD (B_ * H_ * S_ * D_)   // 262144 floats per tensor
#define LOG2E 1.44269504088896f

// ---------------------------------------------------------------------------
// Kernel A: fused QKV projection (16 rows/block).
//   q/k/v[e] = sum_c x[row][c] * W[e][c] + b[e], written in (B,H,S,D) layout.
//   Q and K pre-scaled by log2(e) so attention uses bare exp2 (v_exp_f32).
// grid = (128, 3), block = 128.
// ---------------------------------------------------------------------------
__global__ __launch_bounds__(128) void qkv_kernel(
    const float* __restrict__ x,
    const float* __restrict__ Wq, const float* __restrict__ bq,
    const float* __restrict__ Wk, const float* __restrict__ bk,
    const float* __restrict__ Wv, const float* __restrict__ bv,
    float* __restrict__ ws) {
  const int mat = blockIdx.y;
  const float* W    = (mat == 0) ? Wq : (mat == 1) ? Wk : Wv;
  const float* bias = (mat == 0) ? bq : (mat == 1) ? bk : bv;
  const float scale = (mat == 2) ? 1.0f : LOG2E;
  float* outbase = ws + (size_t)mat * BHSD;

  const int row0 = blockIdx.x * 16;
  const int t = threadIdx.x;

  __shared__ __align__(16) float xs[16 * E_];
  const float4* xg = (const float4*)(x + (size_t)row0 * E_);
  float4* xs4 = (float4*)xs;
  #pragma unroll
  for (int i = 0; i < 4; ++i) xs4[t + i * 128] = xg[t + i * 128];
  __syncthreads();

  const int col = t;
  const float4* W4 = (const float4*)(W + (size_t)col * E_);

  float acc[16];
  #pragma unroll
  for (int r = 0; r < 16; ++r) acc[r] = 0.f;

  #pragma unroll 2
  for (int c4 = 0; c4 < E_ / 4; ++c4) {
    float4 w = W4[c4];
    #pragma unroll
    for (int r = 0; r < 16; ++r) {
      float4 xv = xs4[r * (E_ / 4) + c4];
      acc[r] += xv.x * w.x + xv.y * w.y + xv.z * w.z + xv.w * w.w;
    }
  }

  const float bcol = bias[col];
  const int h = col >> 5, d = col & 31;
  #pragma unroll
  for (int r = 0; r < 16; ++r) {
    int row = row0 + r;
    int b = row >> 10, s = row & 1023;
    outbase[(((size_t)(b * H_ + h)) * S_ + s) * D_ + d] = (acc[r] + bcol) * scale;
  }
}

// ---------------------------------------------------------------------------
// Kernel B: ultrametric attention partials, d-split + 8-key phase batching.
//   Lane (h = lane>>5, r = lane&31) owns HALF a Q row: q[16], o[16] in VGPRs.
//   Wave = 32 rows x 2 halves; wave w covers keys [kc*256 + w*32, +32).
//   Per 8-key batch, three phases:
//     P1: 8 independent Chebyshev half-dist trees (ILP hides LDS + max-tree)
//     P2: 8 batched __shfl_xor(.,32) + exp2  (bpermute latency paid once)
//     P3: 8x16 FMA stream, V from global (L1-resident chunk)
//   dist >= 0 so p = exp2(-dist_scaled) needs no online rescaling in fp32.
// grid = 256 row-tiles * 4 kc = 1024 blocks, block = 512 (8 waves).
// LDS union: K-stage [256][32] f32 (32 KB) during loop; merge buffers
// sm_o[8][32][36] + sm_l[8][32] (37.9 KB) after a barrier.
// ---------------------------------------------------------------------------
#define SMEM_BYTES (8 * 32 * 36 * 4 + 8 * 32 * 4)   // 37888

__global__ __launch_bounds__(512)
void attn_kernel(
    const float* __restrict__ qg, const float* __restrict__ kg,
    const float* __restrict__ vg,
    float* __restrict__ part_o, float* __restrict__ part_l) {
  __shared__ __align__(16) char smem[SMEM_BYTES];
  float* ks = (float*)smem;                               // [256][32]
  float (*sm_o)[32][36] = (float (*)[32][36])smem;        // after loop
  float* sm_l = (float*)(smem + 8 * 32 * 36 * 4);         // [8][32]

  const int rt = blockIdx.x >> 2;      // row tile 0..255 (32 rows each)
  const int kc = blockIdx.x & 3;       // key chunk 0..3
  const int t = threadIdx.x;
  const int w = t >> 6;                // wave 0..7
  const int lane = t & 63;
  const int h = lane >> 5;             // d-half 0..1
  const int r = lane & 31;             // row within tile
  const int bh = rt >> 5;              // head index (b*H + h) 0..7
  const int srow = (rt & 31) * 32 + r;

  const float* kbase = kg + (size_t)bh * S_ * D_;
  const float* vbase = vg + (size_t)bh * S_ * D_;

  // ---- cooperative stage of this block's 256-key K chunk: 2048 float4 ----
  {
    const float4* kgt = (const float4*)(kbase + (size_t)kc * 256 * D_);
    float4* ks4 = (float4*)ks;
    #pragma unroll
    for (int i = 0; i < 4; ++i) {
      int f = t + i * 512;
      ks4[f] = kgt[f];
    }
  }

  // ---- my Q half-row -> registers ----
  const float* qrow = qg + ((size_t)bh * S_ + srow) * D_ + h * 16;
  float4 q0 = *(const float4*)(qrow + 0);
  float4 q1 = *(const float4*)(qrow + 4);
  float4 q2 = *(const float4*)(qrow + 8);
  float4 q3 = *(const float4*)(qrow + 12);

  float o[16];
  #pragma unroll
  for (int i = 0; i < 16; ++i) o[i] = 0.f;
  float l = 0.f;

  __syncthreads();   // K staged

  const float* kLds = ks + (size_t)(w * 32) * D_ + h * 16;
  const float* vGlb = vbase + ((size_t)(kc * 256) + w * 32) * D_ + h * 16;

  for (int b = 0; b < 4; ++b) {
    const int b8 = b * 8;

    // ---- P1: 8 independent half-dist trees ----
    float dh[8];
    #pragma unroll
    for (int i = 0; i < 8; ++i) {
      const float* kr = kLds + (size_t)(b8 + i) * D_;
      float4 k0 = *(const float4*)(kr + 0);
      float4 k1 = *(const float4*)(kr + 4);
      float4 k2 = *(const float4*)(kr + 8);
      float4 k3 = *(const float4*)(kr + 12);
      float c0 = fmaxf(fabsf(q0.x - k0.x), fabsf(q0.y - k0.y));
      float c1 = fmaxf(fabsf(q0.z - k0.z), fabsf(q0.w - k0.w));
      c0 = fmaxf(c0, fmaxf(fabsf(q1.x - k1.x), fabsf(q1.y - k1.y)));
      c1 = fmaxf(c1, fmaxf(fabsf(q1.z - k1.z), fabsf(q1.w - k1.w)));
      c0 = fmaxf(c0, fmaxf(fabsf(q2.x - k2.x), fabsf(q2.y - k2.y)));
      c1 = fmaxf(c1, fmaxf(fabsf(q2.z - k2.z), fabsf(q2.w - k2.w)));
      c0 = fmaxf(c0, fmaxf(fabsf(q3.x - k3.x), fabsf(q3.y - k3.y)));
      c1 = fmaxf(c1, fmaxf(fabsf(q3.z - k3.z), fabsf(q3.w - k3.w)));
      dh[i] = fmaxf(c0, c1);
    }

    // ---- P2: batched cross-half combine + exp2 ----
    float p[8];
    #pragma unroll
    for (int i = 0; i < 8; ++i) {
      float d2 = fmaxf(dh[i], __shfl_xor(dh[i], 32));
      p[i] = exp2f(-d2);              // dist pre-scaled by log2e
    }

    // ---- P3: FMA stream ----
    #pragma unroll
    for (int i = 0; i < 8; ++i) {
      const float* vr = vGlb + (size_t)(b8 + i) * D_;
      float4 v0 = *(const float4*)(vr + 0);
      float4 v1 = *(const float4*)(vr + 4);
      float4 v2 = *(const float4*)(vr + 8);
      float4 v3 = *(const float4*)(vr + 12);
      const float pi = p[i];
      l += pi;
      o[ 0] = fmaf(pi, v0.x, o[ 0]); o[ 1] = fmaf(pi, v0.y, o[ 1]);
      o[ 2] = fmaf(pi, v0.z, o[ 2]); o[ 3] = fmaf(pi, v0.w, o[ 3]);
      o[ 4] = fmaf(pi, v1.x, o[ 4]); o[ 5] = fmaf(pi, v1.y, o[ 5]);
      o[ 6] = fmaf(pi, v1.z, o[ 6]); o[ 7] = fmaf(pi, v1.w, o[ 7]);
      o[ 8] = fmaf(pi, v2.x, o[ 8]); o[ 9] = fmaf(pi, v2.y, o[ 9]);
      o[10] = fmaf(pi, v2.z, o[10]); o[11] = fmaf(pi, v2.w, o[11]);
      o[12] = fmaf(pi, v3.x, o[12]); o[13] = fmaf(pi, v3.y, o[13]);
      o[14] = fmaf(pi, v3.z, o[14]); o[15] = fmaf(pi, v3.w, o[15]);
    }
  }

  __syncthreads();   // all waves done reading ks -> safe to reuse LDS

  // ---- write per-wave half-partials, merge 8 waves, write raw partial ----
  {
    float* dst = &sm_o[w][r][h * 16];
    #pragma unroll
    for (int e = 0; e < 4; ++e)
      *(float4*)(dst + e * 4) = make_float4(o[e*4+0], o[e*4+1], o[e*4+2], o[e*4+3]);
    if (h == 0) sm_l[w * 32 + r] = l;
  }
  __syncthreads();

  #pragma unroll
  for (int pi = 0; pi < 2; ++pi) {
    const int id = t + pi * 512;       // 0..1023 = 32 rows x 32 dims
    const int rr = id >> 5, dd = id & 31;
    float s = 0.f;
    #pragma unroll
    for (int ww = 0; ww < 8; ++ww) s += sm_o[ww][rr][dd];
    part_o[((size_t)(rt * 4 + kc) * 32 + rr) * 32 + dd] = s;
  }
  if (t < 32) {
    float s = 0.f;
    #pragma unroll
    for (int ww = 0; ww < 8; ++ww) s += sm_l[ww * 32 + t];
    part_l[(size_t)(rt * 4 + kc) * 32 + t] = s;
  }
}

// ---------------------------------------------------------------------------
// Kernel C: merge kc-partials -> att rows in LDS -> out = att @ Wo^T + bo
// grid = 128 blocks (16 flat rows each), block = 128.
// ---------------------------------------------------------------------------
__global__ __launch_bounds__(128) void out_kernel(
    const float* __restrict__ part_o, const float* __restrict__ part_l,
    const float* __restrict__ Wo, const float* __restrict__ bo,
    float* __restrict__ out) {
  const int row0 = blockIdx.x * 16;
  const int t = threadIdx.x;

  __shared__ __align__(16) float xs[16 * E_];

  const int e = t;
  const int h = e >> 5, d = e & 31;
  #pragma unroll
  for (int i = 0; i < 16; ++i) {
    const int r = row0 + i;
    const int b = r >> 10, s = r & 1023;
    const int rt = (b * H_ + h) * 32 + (s >> 5);   // 32-row tiles
    const int lrow = s & 31;
    float acc = 0.f, lsum = 0.f;
    #pragma unroll
    for (int kc = 0; kc < 4; ++kc) {
      const size_t base = (size_t)(rt * 4 + kc) * 32 + lrow;
      acc  += part_o[base * 32 + d];
      lsum += part_l[base];
    }
    xs[i * E_ + e] = acc / lsum;
  }
  __syncthreads();

  const int col = t;
  const float4* W4 = (const float4*)(Wo + (size_t)col * E_);
  const float4* xs4 = (const float4*)xs;

  float acc[16];
  #pragma unroll
  for (int r = 0; r < 16; ++r) acc[r] = 0.f;

  #pragma unroll 2
  for (int c4 = 0; c4 < E_ / 4; ++c4) {
    float4 w = W4[c4];
    #pragma unroll
    for (int r = 0; r < 16; ++r) {
      float4 xv = xs4[r * (E_ / 4) + c4];
      acc[r] += xv.x * w.x + xv.y * w.y + xv.z * w.z + xv.w * w.w;
    }
  }

  const float bcol = bo[col];
  #pragma unroll
  for (int r = 0; r < 16; ++r)
    out[(size_t)(row0 + r) * E_ + col] = acc[r] + bcol;
}

// ---------------------------------------------------------------------------
extern "C" void kernel_launch(void* const* d_in, const int* in_sizes, int n_in,
                              void* d_out, int out_size, void* d_ws, size_t ws_size,
                              hipStream_t stream) {
  const float* x  = (const float*)d_in[0];
  const float* Wq = (const float*)d_in[1];
  const float* bq = (const float*)d_in[2];
  const float* Wk = (const float*)d_in[3];
  const float* bk = (const float*)d_in[4];
  const float* Wv = (const float*)d_in[5];
  const float* bv = (const float*)d_in[6];
  const float* Wo = (const float*)d_in[7];
  const float* bo = (const float*)d_in[8];
  float* ws  = (float*)d_ws;
  float* out = (float*)d_out;

  // ws layout (floats):
  //   [0, BHSD)          q (log2e-scaled)
  //   [BHSD, 2*BHSD)     k (log2e-scaled)
  //   [2*BHSD, 3*BHSD)   v
  //   [3*BHSD, +1048576) part_o : [256 rt][4 kc][32 row][32 d]
  //   then 32768         part_l : [256 rt][4 kc][32 row]
  float* qd = ws;
  float* kd = ws + (size_t)BHSD;
  float* vd = ws + 2 * (size_t)BHSD;
  float* part_o = ws + 3 * (size_t)BHSD;
  float* part_l = part_o + (size_t)256 * 4 * 32 * 32;

  qkv_kernel<<<dim3((B_ * S_) / 16, 3), 128, 0, stream>>>(x, Wq, bq, Wk, bk, Wv, bv, ws);
  attn_kernel<<<dim3(256 * 4), 512, 0, stream>>>(qd, kd, vd, part_o, part_l);
  out_kernel<<<dim3((B_ * S_) / 16), 128, 0, stream>>>(part_o, part_l, Wo, bo, out);
}

// Round 8
// 50.670 us; speedup vs baseline: 1.8027x; 1.8027x over previous
//
#include <hip/hip_runtime.h>
#include <hip/hip_bf16.h>

#define B_ 2
#define S_ 1024
#define E_ 128
#define H_ 4
#define D_ 32
#define BHSD (B_ * H_ * S_ * D_)   // 262144 floats per tensor
#define LOG2E 1.44269504088896f

// ---------------------------------------------------------------------------
// Kernel A: fused QKV projection (8 rows/block — validated R5 version).
//   Q and K pre-scaled by log2(e) so attention uses bare exp2.
// ---------------------------------------------------------------------------
__global__ __launch_bounds__(128) void qkv_kernel(
    const float* __restrict__ x,
    const float* __restrict__ Wq, const float* __restrict__ bq,
    const float* __restrict__ Wk, const float* __restrict__ bk,
    const float* __restrict__ Wv, const float* __restrict__ bv,
    float* __restrict__ ws) {
  const int mat = blockIdx.y;
  const float* W    = (mat == 0) ? Wq : (mat == 1) ? Wk : Wv;
  const float* bias = (mat == 0) ? bq : (mat == 1) ? bk : bv;
  const float scale = (mat == 2) ? 1.0f : LOG2E;
  float* outbase = ws + (size_t)mat * BHSD;

  const int row0 = blockIdx.x * 8;
  const int t = threadIdx.x;

  __shared__ __align__(16) float xs[8 * E_];
  const float4* xg = (const float4*)(x + (size_t)row0 * E_);
  float4* xs4 = (float4*)xs;
  #pragma unroll
  for (int i = 0; i < 2; ++i) xs4[t + i * 128] = xg[t + i * 128];
  __syncthreads();

  const int col = t;
  const float4* W4 = (const float4*)(W + (size_t)col * E_);

  float acc[8];
  #pragma unroll
  for (int r = 0; r < 8; ++r) acc[r] = 0.f;

  #pragma unroll 4
  for (int c4 = 0; c4 < E_ / 4; ++c4) {
    float4 w = W4[c4];
    #pragma unroll
    for (int r = 0; r < 8; ++r) {
      float4 xv = xs4[r * (E_ / 4) + c4];
      acc[r] += xv.x * w.x + xv.y * w.y + xv.z * w.z + xv.w * w.w;
    }
  }

  const float bcol = bias[col];
  const int h = col >> 5, d = col & 31;
  #pragma unroll
  for (int r = 0; r < 8; ++r) {
    int row = row0 + r;
    int b = row >> 10, s = row & 1023;
    outbase[(((size_t)(b * H_ + h)) * S_ + s) * D_ + d] = (acc[r] + bcol) * scale;
  }
}

// ---------------------------------------------------------------------------
// Kernel B: ultrametric attention as two register-tiled "GEMMs".
//   Block = 64 Q-rows x 256 keys (kc chunk), 256 threads (4 waves).
//   Per 64-key iteration:
//     DIST: wave w covers keys [w*16, +16); lane (rg=lane>>3, kg=lane&7)
//           owns 8 rows {rg+8i} x 2 keys {w*16+kg+8j}: dist[8][2] accumulated
//           over 8 d-chunks from LDS (b128, broadcast, conflict-free pads).
//     p = exp2(-dist); written transposed to Ps[key][storage_row] where
//           storage_row rg*8+i <-> actual row rg+8i (lane rows contiguous).
//     PV:   lane (rg, dg=lane&7) owns O[8 rows {rg+8i}][4 dims {dg*4..}];
//           per key: p b128 + V b128 (broadcast) + 32 FMA; 16 keys per wave.
//   l kept per-lane (8 rows), kg-shfl-reduced once at the end.
//   End: 4-wave O/l merge in LDS (reusing K/V/P buffers), one raw partial
//   per (rowtile, kc) written -> out_kernel (R3-validated) merges 4 kc.
// grid = 8 heads * 16 rowtiles * 4 kc = 512 blocks.
// ---------------------------------------------------------------------------
#define QSTRIDE 36
#define PSTRIDE 68

__global__ __launch_bounds__(256) void attn_kernel(
    const float* __restrict__ qg, const float* __restrict__ kg_,
    const float* __restrict__ vg,
    float* __restrict__ part_o, float* __restrict__ part_l) {
  __shared__ __align__(16) float Qs[64 * QSTRIDE];   //  9216 B
  __shared__ __align__(16) float Ks[64 * QSTRIDE];   //  9216 B
  __shared__ __align__(16) float Vs[64 * QSTRIDE];   //  9216 B
  __shared__ __align__(16) float Ps[64 * PSTRIDE];   // 17408 B (tail reused for l)

  const int bx = blockIdx.x;
  const int kc  = bx & 3;
  const int rtl = (bx >> 2) & 15;     // row tile within head
  const int head = bx >> 6;           // b*H + h, 0..7
  const int t = threadIdx.x;
  const int w = t >> 6;               // wave 0..3
  const int lane = t & 63;
  const int rg = lane >> 3;           // row group: rows {rg + 8i}
  const int kg = lane & 7;            // key group (dist) / dim group (PV)

  const float* qbase = qg  + (size_t)head * S_ * D_ + (size_t)rtl * 64 * D_;
  const float* kbase = kg_ + (size_t)head * S_ * D_ + (size_t)kc * 256 * D_;
  const float* vbase = vg  + (size_t)head * S_ * D_ + (size_t)kc * 256 * D_;

  // ---- stage Q tile once: 64x32 = 512 float4 ----
  {
    const float4* src = (const float4*)qbase;
    #pragma unroll
    for (int i = 0; i < 2; ++i) {
      int f = t + i * 256;            // 0..511
      int r = f >> 3, c4 = f & 7;
      *(float4*)(Qs + r * QSTRIDE + c4 * 4) = src[f];
    }
  }

  float O[8][4];
  #pragma unroll
  for (int i = 0; i < 8; ++i)
    #pragma unroll
    for (int c = 0; c < 4; ++c) O[i][c] = 0.f;
  float lrow[8];
  #pragma unroll
  for (int i = 0; i < 8; ++i) lrow[i] = 0.f;

  for (int it = 0; it < 4; ++it) {
    // ---- stage K,V 64-key tiles ----
    {
      const float4* ksrc = (const float4*)(kbase + (size_t)it * 64 * D_);
      const float4* vsrc = (const float4*)(vbase + (size_t)it * 64 * D_);
      #pragma unroll
      for (int i = 0; i < 2; ++i) {
        int f = t + i * 256;
        int r = f >> 3, c4 = f & 7;
        *(float4*)(Ks + r * QSTRIDE + c4 * 4) = ksrc[f];
        *(float4*)(Vs + r * QSTRIDE + c4 * 4) = vsrc[f];
      }
    }
    __syncthreads();

    // ---- DIST: dist[8 rows][2 keys] over 8 d-chunks ----
    float dist[8][2];
    #pragma unroll
    for (int i = 0; i < 8; ++i) { dist[i][0] = 0.f; dist[i][1] = 0.f; }

    #pragma unroll 2
    for (int c = 0; c < 8; ++c) {
      float4 qv[8];
      #pragma unroll
      for (int i = 0; i < 8; ++i)
        qv[i] = *(const float4*)(Qs + (rg + 8 * i) * QSTRIDE + c * 4);
      float4 kv[2];
      #pragma unroll
      for (int j = 0; j < 2; ++j)
        kv[j] = *(const float4*)(Ks + (w * 16 + kg + 8 * j) * QSTRIDE + c * 4);
      #pragma unroll
      for (int i = 0; i < 8; ++i) {
        #pragma unroll
        for (int j = 0; j < 2; ++j) {
          float m0 = fmaxf(fabsf(qv[i].x - kv[j].x), fabsf(qv[i].y - kv[j].y));
          float m1 = fmaxf(fabsf(qv[i].z - kv[j].z), fabsf(qv[i].w - kv[j].w));
          dist[i][j] = fmaxf(dist[i][j], fmaxf(m0, m1));
        }
      }
    }

    // ---- p = exp2(-dist); accumulate l; write P transposed ----
    float pp[8][2];
    #pragma unroll
    for (int i = 0; i < 8; ++i) {
      #pragma unroll
      for (int j = 0; j < 2; ++j) {
        float p = exp2f(-dist[i][j]);     // dist pre-scaled by log2e
        pp[i][j] = p;
        lrow[i] += p;
      }
    }
    #pragma unroll
    for (int j = 0; j < 2; ++j) {
      float* dst = Ps + (w * 16 + kg + 8 * j) * PSTRIDE + rg * 8;
      *(float4*)(dst + 0) = make_float4(pp[0][j], pp[1][j], pp[2][j], pp[3][j]);
      *(float4*)(dst + 4) = make_float4(pp[4][j], pp[5][j], pp[6][j], pp[7][j]);
    }
    __syncthreads();

    // ---- PV: O[8r][4d] += sum over this wave's 16 keys ----
    const int tk0 = w * 16;
    #pragma unroll 4
    for (int u = 0; u < 16; ++u) {
      const int tk = tk0 + u;
      float4 pa = *(const float4*)(Ps + tk * PSTRIDE + rg * 8);
      float4 pb = *(const float4*)(Ps + tk * PSTRIDE + rg * 8 + 4);
      float4 vv = *(const float4*)(Vs + tk * QSTRIDE + kg * 4);
      O[0][0] = fmaf(pa.x, vv.x, O[0][0]); O[0][1] = fmaf(pa.x, vv.y, O[0][1]);
      O[0][2] = fmaf(pa.x, vv.z, O[0][2]); O[0][3] = fmaf(pa.x, vv.w, O[0][3]);
      O[1][0] = fmaf(pa.y, vv.x, O[1][0]); O[1][1] = fmaf(pa.y, vv.y, O[1][1]);
      O[1][2] = fmaf(pa.y, vv.z, O[1][2]); O[1][3] = fmaf(pa.y, vv.w, O[1][3]);
      O[2][0] = fmaf(pa.z, vv.x, O[2][0]); O[2][1] = fmaf(pa.z, vv.y, O[2][1]);
      O[2][2] = fmaf(pa.z, vv.z, O[2][2]); O[2][3] = fmaf(pa.z, vv.w, O[2][3]);
      O[3][0] = fmaf(pa.w, vv.x, O[3][0]); O[3][1] = fmaf(pa.w, vv.y, O[3][1]);
      O[3][2] = fmaf(pa.w, vv.z, O[3][2]); O[3][3] = fmaf(pa.w, vv.w, O[3][3]);
      O[4][0] = fmaf(pb.x, vv.x, O[4][0]); O[4][1] = fmaf(pb.x, vv.y, O[4][1]);
      O[4][2] = fmaf(pb.x, vv.z, O[4][2]); O[4][3] = fmaf(pb.x, vv.w, O[4][3]);
      O[5][0] = fmaf(pb.y, vv.x, O[5][0]); O[5][1] = fmaf(pb.y, vv.y, O[5][1]);
      O[5][2] = fmaf(pb.y, vv.z, O[5][2]); O[5][3] = fmaf(pb.y, vv.w, O[5][3]);
      O[6][0] = fmaf(pb.z, vv.x, O[6][0]); O[6][1] = fmaf(pb.z, vv.y, O[6][1]);
      O[6][2] = fmaf(pb.z, vv.z, O[6][2]); O[6][3] = fmaf(pb.z, vv.w, O[6][3]);
      O[7][0] = fmaf(pb.w, vv.x, O[7][0]); O[7][1] = fmaf(pb.w, vv.y, O[7][1]);
      O[7][2] = fmaf(pb.w, vv.z, O[7][2]); O[7][3] = fmaf(pb.w, vv.w, O[7][3]);
    }
    __syncthreads();   // PV reads done -> safe to restage K/V/P
  }

  // ---- reduce l across kg lanes (butterfly over lane bits 0..2) ----
  #pragma unroll
  for (int i = 0; i < 8; ++i) {
    lrow[i] += __shfl_xor(lrow[i], 1);
    lrow[i] += __shfl_xor(lrow[i], 2);
    lrow[i] += __shfl_xor(lrow[i], 4);
  }

  // ---- 4-wave O merge reusing LDS buffers; l via Ps tail ----
  float* slbuf = Ps + 64 * 64;        // 256 floats, disjoint from [64][36] region
  if (kg == 0) {
    #pragma unroll
    for (int i = 0; i < 8; ++i) slbuf[w * 64 + (rg + 8 * i)] = lrow[i];
  }
  if (w == 1) {
    #pragma unroll
    for (int i = 0; i < 8; ++i)
      *(float4*)(Ks + (rg + 8 * i) * QSTRIDE + kg * 4) =
          make_float4(O[i][0], O[i][1], O[i][2], O[i][3]);
  } else if (w == 2) {
    #pragma unroll
    for (int i = 0; i < 8; ++i)
      *(float4*)(Vs + (rg + 8 * i) * QSTRIDE + kg * 4) =
          make_float4(O[i][0], O[i][1], O[i][2], O[i][3]);
  } else if (w == 3) {
    #pragma unroll
    for (int i = 0; i < 8; ++i)
      *(float4*)(Qs + (rg + 8 * i) * QSTRIDE + kg * 4) =
          make_float4(O[i][0], O[i][1], O[i][2], O[i][3]);
  }
  __syncthreads();

  if (w == 0) {
    const size_t base = ((size_t)(head * 16 + rtl) * 4 + kc) * 64;
    #pragma unroll
    for (int i = 0; i < 8; ++i) {
      const int ar = rg + 8 * i;
      float4 a = *(const float4*)(Ks + ar * QSTRIDE + kg * 4);
      float4 b = *(const float4*)(Vs + ar * QSTRIDE + kg * 4);
      float4 c = *(const float4*)(Qs + ar * QSTRIDE + kg * 4);
      float4 r;
      r.x = O[i][0] + a.x + b.x + c.x;
      r.y = O[i][1] + a.y + b.y + c.y;
      r.z = O[i][2] + a.z + b.z + c.z;
      r.w = O[i][3] + a.w + b.w + c.w;
      *(float4*)(part_o + (base + ar) * 32 + kg * 4) = r;
    }
    if (kg == 0) {
      #pragma unroll
      for (int i = 0; i < 8; ++i) {
        const int ar = rg + 8 * i;
        part_l[base + ar] = slbuf[0 * 64 + ar] + slbuf[1 * 64 + ar] +
                            slbuf[2 * 64 + ar] + slbuf[3 * 64 + ar];
      }
    }
  }
}

// ---------------------------------------------------------------------------
// Kernel C: merge kc-partials -> att rows in LDS -> out = att @ Wo^T + bo
// (R3-validated version; part layout [rt(64-row)][4 kc][64 row][32 d])
// ---------------------------------------------------------------------------
__global__ __launch_bounds__(128) void out_kernel(
    const float* __restrict__ part_o, const float* __restrict__ part_l,
    const float* __restrict__ Wo, const float* __restrict__ bo,
    float* __restrict__ out) {
  const int row0 = blockIdx.x * 8;
  const int t = threadIdx.x;

  __shared__ __align__(16) float xs[8 * E_];

  const int e = t;
  const int h = e >> 5, d = e & 31;
  #pragma unroll
  for (int i = 0; i < 8; ++i) {
    const int r = row0 + i;
    const int b = r >> 10, s = r & 1023;
    const int rt = (b * H_ + h) * 16 + (s >> 6);
    const int lrow = s & 63;
    float acc = 0.f, lsum = 0.f;
    #pragma unroll
    for (int kc = 0; kc < 4; ++kc) {
      const size_t base = (size_t)(rt * 4 + kc) * 64 + lrow;
      acc  += part_o[base * 32 + d];
      lsum += part_l[base];
    }
    xs[i * E_ + e] = acc / lsum;
  }
  __syncthreads();

  const int col = t;
  const float4* W4 = (const float4*)(Wo + (size_t)col * E_);
  const float4* xs4 = (const float4*)xs;

  float acc[8];
  #pragma unroll
  for (int r = 0; r < 8; ++r) acc[r] = 0.f;

  #pragma unroll 4
  for (int c4 = 0; c4 < E_ / 4; ++c4) {
    float4 w = W4[c4];
    #pragma unroll
    for (int r = 0; r < 8; ++r) {
      float4 xv = xs4[r * (E_ / 4) + c4];
      acc[r] += xv.x * w.x + xv.y * w.y + xv.z * w.z + xv.w * w.w;
    }
  }

  const float bcol = bo[col];
  #pragma unroll
  for (int r = 0; r < 8; ++r)
    out[(size_t)(row0 + r) * E_ + col] = acc[r] + bcol;
}

// ---------------------------------------------------------------------------
extern "C" void kernel_launch(void* const* d_in, const int* in_sizes, int n_in,
                              void* d_out, int out_size, void* d_ws, size_t ws_size,
                              hipStream_t stream) {
  const float* x  = (const float*)d_in[0];
  const float* Wq = (const float*)d_in[1];
  const float* bq = (const float*)d_in[2];
  const float* Wk = (const float*)d_in[3];
  const float* bk = (const float*)d_in[4];
  const float* Wv = (const float*)d_in[5];
  const float* bv = (const float*)d_in[6];
  const float* Wo = (const float*)d_in[7];
  const float* bo = (const float*)d_in[8];
  float* ws  = (float*)d_ws;
  float* out = (float*)d_out;

  // ws layout (floats):
  //   [0, BHSD)          q (log2e-scaled)
  //   [BHSD, 2*BHSD)     k (log2e-scaled)
  //   [2*BHSD, 3*BHSD)   v
  //   [3*BHSD, +1048576) part_o : [128 rt][4 kc][64 row][32 d]
  //   then 32768         part_l : [128 rt][4 kc][64 row]
  float* qd = ws;
  float* kd = ws + (size_t)BHSD;
  float* vd = ws + 2 * (size_t)BHSD;
  float* part_o = ws + 3 * (size_t)BHSD;
  float* part_l = part_o + (size_t)128 * 4 * 64 * 32;

  qkv_kernel<<<dim3((B_ * S_) / 8, 3), 128, 0, stream>>>(x, Wq, bq, Wk, bk, Wv, bv, ws);
  attn_kernel<<<dim3(512), 256, 0, stream>>>(qd, kd, vd, part_o, part_l);
  out_kernel<<<dim3((B_ * S_) / 8), 128, 0, stream>>>(part_o, part_l, Wo, bo, out);
}